// Round 3
// baseline (111.798 us; speedup 1.0000x reference)
//
#include <hip/hip_runtime.h>

#define SEQ    2048
#define N_PTS  8192
#define NK     32768   // N * K_NEG
#define N2     16384   // 2 * N
#define NACC   22
#define NLOSSBLK 256
#define SLOT_DOUBLES (NLOSSBLK * NACC)      // 5632 doubles
#define CTR_OFFSET   (SLOT_DOUBLES * 8)     // byte offset of ticket counter in d_ws

__device__ __forceinline__ float frcp(float x)  { return __builtin_amdgcn_rcpf(x); }
__device__ __forceinline__ float fsqrt_(float x){ return __builtin_amdgcn_sqrtf(x); }

__device__ __forceinline__ float min_dist2(float4 a, float4 b, const float* __restrict__ wc)
{
    float best = 3.4e38f;
    #pragma unroll
    for (int w = 0; w < 16; ++w) {
        const float* c = &wc[w * 8];
        float d, s;
        d = a.x - c[0]; s = d * d;
        d = a.y - c[1]; s = fmaf(d, d, s);
        d = a.z - c[2]; s = fmaf(d, d, s);
        d = a.w - c[3]; s = fmaf(d, d, s);
        d = b.x - c[4]; s = fmaf(d, d, s);
        d = b.y - c[5]; s = fmaf(d, d, s);
        d = b.z - c[6]; s = fmaf(d, d, s);
        d = b.w - c[7]; s = fmaf(d, d, s);
        best = fminf(best, s);
    }
    return best;
}

// ---------------------------------------------------------------------------
// One fused kernel, 512 blocks x 256 threads.
//
// blocks 0..255 (forces): block = (batch, 32-wide i-tile). Thread =
//   (i-group of 4) x (j-slice: 64 j's at stride 32).  Register-blocking 4 i
//   per thread gives 4 independent dep chains per LDS read pair
//   (ds_read_b64 pos + ds_read_b32 mass) -> latency hidden at 1 wave/SIMD.
//   (R2 post-mortem: 1-i version was latency-bound, 40us @ VALUBusy 23%.)
//   rf[][32][33]: +1 pad breaks the 32-way bank conflict on partial stores.
//
// blocks 256..511 (loss): per-block partial sums -> slot in d_ws; last-
//   arriving block (device ticket) reduces slots and finalizes the loss.
// ---------------------------------------------------------------------------
__global__ __launch_bounds__(256) void fused_kernel(
    const float* __restrict__ pos,    // [N,2]
    const float* __restrict__ mass,   // [N]
    const float* __restrict__ vel,    // [N,2]
    const float* __restrict__ pos8,   // [N,8]
    const float* __restrict__ pp2,    // [N,2]
    const float* __restrict__ pp8,    // [N,8]
    const float* __restrict__ pmass,  // [N]
    const float* __restrict__ negp2,  // [NK,2]
    const float* __restrict__ negp8,  // [NK,8]
    const float* __restrict__ negm,   // [NK]
    const float* __restrict__ expm,   // [NK]
    const float* __restrict__ Gptr,
    const float* __restrict__ Rptr,
    const float* __restrict__ wellc,  // [16,8]
    const float* __restrict__ wstr,
    const float* __restrict__ tPtr,
    const float* __restrict__ ecPtr,
    float* __restrict__ out,          // [16385]
    double* __restrict__ slots,       // [256][22] in d_ws
    unsigned int* __restrict__ ctr)   // ticket counter in d_ws (memset to 0)
{
    const int tid = threadIdx.x;
    const int blk = blockIdx.x;

    if (blk < 256) {
        // ----------------------------- FORCES -----------------------------
        __shared__ float2 sxy[SEQ];        // 16 KB
        __shared__ float  sm[SEQ];         //  8 KB
        __shared__ float  rf[2][32][33];   //  8.25 KB (+1 pad: no bank conflict)

        const int b  = blk >> 6;           // 0..3
        const int it = blk & 63;           // 0..63  (32-wide i tile)
        const int rowbase = b * SEQ;

        const float2* p2 = (const float2*)pos;
        #pragma unroll
        for (int k0 = 0; k0 < SEQ; k0 += 256) {
            const int k = k0 + tid;
            sxy[k] = p2[rowbase + k];
            sm[k]  = mass[rowbase + k];
        }
        const float Gv = fmaxf(Gptr[0], 0.0f);
        const float Rv = fmaxf(Rptr[0], 0.0f);
        __syncthreads();

        const int ig = tid >> 5;           // 0..7  (i-group)
        const int js = tid & 31;           // 0..31 (j-slice)
        const int i0 = ig * 4;

        float px[4], py[4], ci[4];
        float fx[4] = {0.f, 0.f, 0.f, 0.f};
        float fy[4] = {0.f, 0.f, 0.f, 0.f};
        #pragma unroll
        for (int s = 0; s < 4; ++s) {
            const int iloc = it * 32 + i0 + s;
            px[s] = sxy[iloc].x;
            py[s] = sxy[iloc].y;
            ci[s] = Gv * sm[iloc];         // G+ * m_i
        }

        #pragma unroll 4
        for (int jj = 0; jj < 64; ++jj) {
            const int j = jj * 32 + js;    // stride-32: conflict-free LDS
            const float2 pj = sxy[j];
            const float  mj = sm[j];
            #pragma unroll
            for (int s = 0; s < 4; ++s) {
                const float dx = pj.x - px[s];     // diff = pos_j - pos_i
                const float dy = pj.y - py[s];
                const float r2 = fmaf(dx, dx, fmaf(dy, dy, 1e-6f));
                const float r  = fsqrt_(r2);
                const float rp = r + 1e-9f;
                const float tpos = fmaxf(fmaf(-10.0f, r, 1.0f), 0.0f); // relu(1-r/.1)
                const float mor = (Rv * tpos) * frcp(fmaf(r2, r, 1e-9f) * rp)
                                - (ci[s] * mj) * frcp(r2 * rp);
                fx[s] = fmaf(mor, dx, fx[s]);      // diag: dx=dy=0 -> 0 exactly
                fy[s] = fmaf(mor, dy, fy[s]);
            }
        }

        #pragma unroll
        for (int s = 0; s < 4; ++s) {
            rf[0][js][i0 + s] = fx[s];
            rf[1][js][i0 + s] = fy[s];
        }
        __syncthreads();
        if (tid < 64) {
            const int c = tid >> 5, i = tid & 31;
            float sum = 0.f;
            #pragma unroll
            for (int q = 0; q < 32; ++q) sum += rf[c][q][i];
            out[(rowbase + it * 32 + i) * 2 + c] = sum;
        }
        return;
    }

    // ------------------------------- LOSS ---------------------------------
    __shared__ float  wc[128];
    __shared__ double red[4][NACC];
    __shared__ int    lastflag;

    if (tid < 128) wc[tid] = wellc[tid];
    if (tid == 0)  lastflag = 0;
    __syncthreads();

    const int lb  = blk - 256;            // 0..255
    const int idx = lb * 256 + tid;       // [0, 65536)

    double acc[NACC];
    #pragma unroll
    for (int k = 0; k < NACC; ++k) acc[k] = 0.0;

    {   // well_neg row: first NK rows are repeat(pos8, K), then neg_pos_8d
        const float* row = (idx < NK) ? (pos8 + (idx >> 2) * 8)
                                      : (negp8 + (idx - NK) * 8);
        const float4 a = ((const float4*)row)[0];
        const float4 b = ((const float4*)row)[1];
        acc[3] = (double)min_dist2(a, b, wc);
    }
    if (idx < NK) {   // pe_pairwise_neg
        const int i = idx >> 2;
        const float dx = pos[i * 2 + 0] - negp2[idx * 2 + 0];
        const float dy = pos[i * 2 + 1] - negp2[idx * 2 + 1];
        const float d  = fsqrt_(fmaf(dx, dx, dy * dy)) + 1e-9f;
        acc[1] = (double)(expm[idx] * negm[idx] * frcp(d));
    }
    if (idx < N2) {   // well_pos + variance sums over all_pos_8d
        const float* row = (idx < N_PTS) ? (pos8 + idx * 8)
                                         : (pp8 + (idx - N_PTS) * 8);
        const float4 a = ((const float4*)row)[0];
        const float4 b = ((const float4*)row)[1];
        acc[2] = (double)min_dist2(a, b, wc);
        acc[4]  = (double)a.x;  acc[12] = (double)(a.x * a.x);
        acc[5]  = (double)a.y;  acc[13] = (double)(a.y * a.y);
        acc[6]  = (double)a.z;  acc[14] = (double)(a.z * a.z);
        acc[7]  = (double)a.w;  acc[15] = (double)(a.w * a.w);
        acc[8]  = (double)b.x;  acc[16] = (double)(b.x * b.x);
        acc[9]  = (double)b.y;  acc[17] = (double)(b.y * b.y);
        acc[10] = (double)b.z;  acc[18] = (double)(b.z * b.z);
        acc[11] = (double)b.w;  acc[19] = (double)(b.w * b.w);
    }
    if (idx < N_PTS) {   // pe_pairwise_pos, mass sum, ke sum
        const float dx = pos[idx * 2 + 0] - pp2[idx * 2 + 0];
        const float dy = pos[idx * 2 + 1] - pp2[idx * 2 + 1];
        const float d  = fsqrt_(fmaf(dx, dx, dy * dy)) + 1e-9f;
        acc[0]  = (double)(mass[idx] * pmass[idx] * frcp(d));
        acc[20] = (double)mass[idx];
        const float vx = vel[idx * 2 + 0];
        const float vy = vel[idx * 2 + 1];
        acc[21] = (double)fmaf(vx, vx, vy * vy);
    }

    // block reduction: wave64 shuffle, then cross-wave via LDS
    const int lane = tid & 63, wid = tid >> 6;
    #pragma unroll
    for (int k = 0; k < NACC; ++k) {
        double v = acc[k];
        for (int off = 32; off > 0; off >>= 1) v += __shfl_down(v, off, 64);
        if (lane == 0) red[wid][k] = v;
    }
    __syncthreads();
    if (tid < NACC) {
        slots[lb * NACC + tid] = red[0][tid] + red[1][tid] + red[2][tid] + red[3][tid];
    }
    __syncthreads();                       // slot writes done (block-wide)
    if (tid == 0) {
        __threadfence();                   // release: publish slots
        const unsigned int ticket = atomicAdd(ctr, 1u);
        if (ticket == NLOSSBLK - 1) lastflag = 1;
    }
    __syncthreads();
    if (!lastflag) return;

    // --------- last loss block: reduce all slots + finalize loss ----------
    __threadfence();                       // acquire: see other blocks' slots
    #pragma unroll
    for (int k = 0; k < NACC; ++k) {
        double v = slots[tid * NACC + k];  // tid indexes the 256 slots
        for (int off = 32; off > 0; off >>= 1) v += __shfl_down(v, off, 64);
        if (lane == 0) red[wid][k] = v;
    }
    __syncthreads();
    if (tid == 0) {
        double s[NACC];
        #pragma unroll
        for (int k = 0; k < NACC; ++k)
            s[k] = red[0][k] + red[1][k] + red[2][k] + red[3][k];

        const double Gp  = fmax((double)Gptr[0], 0.0);
        const double wsp = fmax((double)wstr[0], 0.0);
        const double T   = fmax((double)tPtr[0], 0.0);
        const double ec  = fmax((double)ecPtr[0], 0.0);
        const double Nd = 8192.0, NKd = 32768.0, N2d = 16384.0, NK2d = 65536.0;

        const double U_pos = -Gp * s[0] / Nd  + wsp * s[2] / N2d;
        const double U_neg = -Gp * s[1] / NKd + wsp * s[3] / NK2d;

        double var = 0.0;
        for (int d = 0; d < 8; ++d) {
            const double sx_ = s[4 + d], sxx = s[12 + d];
            var += (sxx - sx_ * sx_ / N2d) / (N2d - 1.0);   // ddof=1
        }
        var *= 0.125;
        const double ent = T * ec * var;
        const double Fp = U_pos - ent, Fn = U_neg - ent;
        double fel = 1.0 + Fp - Fn;            // MARGIN + F_pos - F_neg
        if (fel < 0.0) fel = 0.0;
        const double ke_loss = 1e-3 * 0.5 * (s[20] / Nd) * (s[21] / Nd);
        out[16384] = (float)(fel + ke_loss);
    }
}

// ---------------------------------------------------------------------------
extern "C" void kernel_launch(void* const* d_in, const int* in_sizes, int n_in,
                              void* d_out, int out_size, void* d_ws, size_t ws_size,
                              hipStream_t stream)
{
    const float* pos   = (const float*)d_in[0];
    const float* mass  = (const float*)d_in[1];
    const float* vel   = (const float*)d_in[2];
    const float* pos8  = (const float*)d_in[3];
    const float* pp2   = (const float*)d_in[4];
    const float* pp8   = (const float*)d_in[5];
    const float* pmass = (const float*)d_in[6];
    const float* negp2 = (const float*)d_in[7];
    const float* negp8 = (const float*)d_in[8];
    const float* negm  = (const float*)d_in[9];
    const float* expm  = (const float*)d_in[10];
    const float* Gp    = (const float*)d_in[11];
    const float* Rp    = (const float*)d_in[12];
    const float* wellc = (const float*)d_in[13];
    const float* wstr  = (const float*)d_in[14];
    const float* temp  = (const float*)d_in[15];
    const float* ecoef = (const float*)d_in[16];

    float*        out   = (float*)d_out;
    double*       slots = (double*)d_ws;
    unsigned int* ctr   = (unsigned int*)((char*)d_ws + CTR_OFFSET);

    // d_ws is poisoned 0xAA before every launch — only the ticket counter
    // needs zeroing (slots are written before they are read).
    hipMemsetAsync(ctr, 0, sizeof(unsigned int), stream);

    fused_kernel<<<512, 256, 0, stream>>>(pos, mass, vel, pos8, pp2, pp8, pmass,
                                          negp2, negp8, negm, expm, Gp, Rp,
                                          wellc, wstr, temp, ecoef,
                                          out, slots, ctr);
}